// Round 12
// baseline (236.346 us; speedup 1.0000x reference)
//
#include <hip/hip_runtime.h>

#define BB 32
#define TT 1024
#define NN 128
#define YB 256   // y steps buffered in LDS between flushes

// DPP adds — pure VALU cross-lane. ctrl must be a literal.
#define ROR_ADD(p, ctrl)                                                      \
  p += __int_as_float(__builtin_amdgcn_update_dpp(                            \
      0, __float_as_int(p), ctrl, 0xF, 0xF, true));
// row_bcast15 (0x142): lane15 -> lanes16-31, lane47 -> lanes48-63. After
// ror 1,2,4,8 + bcast15, lanes 16..31 (48..63) hold the full 32-lane sum.
#define BCAST15_ADD(p) ROR_ADD(p, 0x142)

// R4 structure (C=4: 32 lanes/row, 8 rows/block, 512 blocks -> 2 waves/SIMD,
// best measured latency tolerance) + R11's W=A*V factoring (per-step coef =
// 1 mul, update = 1 FMA/elem, mask logic hoisted to an init table phase).
__global__ __launch_bounds__(256)
void bdh_seq_kernel(const float* __restrict__ x,
                    const float* __restrict__ w_init,
                    const float* __restrict__ alpha_p,
                    const float* __restrict__ eta_p,
                    const int*   __restrict__ mask,
                    float* __restrict__ out)
{
    const int tid  = threadIdx.x;
    const int bidx = blockIdx.x;           // 512 blocks
    const int b      = bidx & 31;          // batch; %8 pins batch to one XCD L2
    const int i_base = (bidx >> 5) << 3;   // 8 rows per block
    const int rloc   = tid >> 5;           // 0..7 (32 lanes per row)
    const int i      = i_base + rloc;
    const int cg     = tid & 31;
    const int j0     = cg << 2;            // 4 cols per lane

    __shared__ int   mbuf[TT];             // masks (init only)
    __shared__ float Cbuf[TT];             // C[t] = m_t ? eta*invA_t : 0
    __shared__ float Sbuf[TT];             // S[t] = A_{t-1} (group-local)
    __shared__ float Rbuf[TT / 16];        // R[g] = A_15 (group rescale)
    __shared__ float ybuf[YB][8];          // raw dots, scaled by S at flush

    const float alpha = alpha_p[0];
    const float eta   = eta_p[0];
    const float rcp_a = 1.0f / alpha;

    const float* xb = x + (size_t)b * TT * NN;
    const int*   mb = mask + b * TT;
    float* yout = out + (size_t)BB * NN * NN + (size_t)b * TT * NN;

    // ---- init: masks -> LDS, then per-16-step-group decay tables ----
    ((int4*)mbuf)[tid] = ((const int4*)mb)[tid];   // 256 threads x int4 = 1024
    __syncthreads();
    if (tid < 64) {                        // thread g builds group g
        float e_prev = eta;                // e = eta*invA, resets per group
        float e      = eta;
#pragma unroll
        for (int k = 0; k < 16; ++k) {
            const int m = mbuf[tid * 16 + k];
            e = m ? e * rcp_a : e;
            Cbuf[tid * 16 + k] = m ? e : 0.0f;
            Sbuf[tid * 16 + k] = eta / e_prev;   // A_{k-1} (y uses pre-step W)
            e_prev = e;
        }
        Rbuf[tid] = eta / e;               // A_15: end-of-group V rescale
    }
    __syncthreads();

    float4 v = *reinterpret_cast<const float4*>(
        w_init + ((size_t)b * NN + i) * NN + j0);

    // Double-buffered 8-step groups; prefetch distance 8-16 steps.
    float4 Xc[8], Xn[8];
    float  xic[8], xin[8];
    float  Cc[16];
    float  p[16];
    float  Rg;

#define LOADG(X, XI, tbase)                                                   \
  {                                                                           \
    const float* gp = xb + (size_t)(tbase) * NN;                              \
    _Pragma("unroll")                                                         \
    for (int k = 0; k < 8; ++k) {                                             \
      X[k]  = *reinterpret_cast<const float4*>(gp + k * NN + j0);             \
      XI[k] = gp[k * NN + i];                                                 \
    }                                                                         \
  }

// Cbuf reads are wave-uniform addresses -> LDS broadcast, conflict-free.
#define LOADC(tbase)                                                          \
  {                                                                           \
    _Pragma("unroll")                                                         \
    for (int q = 0; q < 4; ++q)                                               \
      *reinterpret_cast<float4*>(&Cc[q * 4]) =                                \
          *reinterpret_cast<const float4*>(&Cbuf[(tbase) + q * 4]);           \
  }

// dot (reads V pre-update) + 1-FMA/elem factored update. ci = C[t]*x_i.
#define COMPG(X, XI, cbase, pbase)                                            \
  {                                                                           \
    _Pragma("unroll")                                                         \
    for (int k = 0; k < 8; ++k) {                                             \
      const float ci = Cc[(cbase) + k] * XI[k];                               \
      float d = v.x * X[k].x;                                                 \
      d = fmaf(v.y, X[k].y, d);                                               \
      d = fmaf(v.z, X[k].z, d);                                               \
      d = fmaf(v.w, X[k].w, d);                                               \
      p[(pbase) + k] = d;                                                     \
      v.x = fmaf(ci, X[k].x, v.x);                                            \
      v.y = fmaf(ci, X[k].y, v.y);                                            \
      v.z = fmaf(ci, X[k].z, v.z);                                            \
      v.w = fmaf(ci, X[k].w, v.w);                                            \
    }                                                                         \
  }

    LOADG(Xc, xic, 0);
    LOADG(Xn, xin, 8);
    LOADC(0);
    Rg = Rbuf[0];

#pragma unroll 1
    for (int t = 0; t < TT; t += 16) {
        COMPG(Xc, xic, 0, 0);
        if (t + 16 < TT) { LOADG(Xc, xic, t + 16); }
        COMPG(Xn, xin, 8, 8);
        if (t + 24 < TT) { LOADG(Xn, xin, t + 24); }

        // end-of-group rescale: V <- A_15 * V  (V == W at group boundaries)
        v.x *= Rg; v.y *= Rg; v.z *= Rg; v.w *= Rg;
        if (t + 16 < TT) { LOADC(t + 16); Rg = Rbuf[(t >> 4) + 1]; }

        // 16 independent 32-lane reduces, stage-outer -> full DPP ILP.
#pragma unroll
        for (int k = 0; k < 16; ++k) { ROR_ADD(p[k], 0x121); }
#pragma unroll
        for (int k = 0; k < 16; ++k) { ROR_ADD(p[k], 0x122); }
#pragma unroll
        for (int k = 0; k < 16; ++k) { ROR_ADD(p[k], 0x124); }
#pragma unroll
        for (int k = 0; k < 16; ++k) { ROR_ADD(p[k], 0x128); }
#pragma unroll
        for (int k = 0; k < 16; ++k) { BCAST15_ADD(p[k]); }

        if (cg == 16) {
#pragma unroll
            for (int k = 0; k < 16; ++k)
                ybuf[(t + k) & (YB - 1)][rloc] = p[k];
        }

        // Flush 256 buffered raw dots, scaled by S[t] (4x per kernel).
        if (((t + 16) & (YB - 1)) == 0) {
            __syncthreads();
            const int t0 = t + 16 - YB;
#pragma unroll
            for (int pass = 0; pass < 8; ++pass) {
                const int idx = (pass << 8) + tid;   // 0..2047
                const int tq  = idx >> 3;            // 0..255
                const int il  = idx & 7;             // row within block
                yout[(size_t)(t0 + tq) * NN + i_base + il] =
                    ybuf[tq][il] * Sbuf[t0 + tq];
            }
            __syncthreads();
        }
    }
#undef LOADG
#undef LOADC
#undef COMPG

    float* wout = out + ((size_t)b * NN + i) * NN + j0;
    *reinterpret_cast<float4*>(wout) = v;
}

extern "C" void kernel_launch(void* const* d_in, const int* in_sizes, int n_in,
                              void* d_out, int out_size, void* d_ws, size_t ws_size,
                              hipStream_t stream)
{
    const float* x      = (const float*)d_in[0];
    const float* w_init = (const float*)d_in[1];
    const float* alpha  = (const float*)d_in[2];
    const float* eta    = (const float*)d_in[3];
    const int*   mask   = (const int*)d_in[4];
    float*       out    = (float*)d_out;

    dim3 grid(512), block(256);
    hipLaunchKernelGGL(bdh_seq_kernel, grid, block, 0, stream,
                       x, w_init, alpha, eta, mask, out);
}